// Round 13
// baseline (180.681 us; speedup 1.0000x reference)
//
#include <hip/hip_runtime.h>
#include <hip/hip_bf16.h>

// Grapher block: RepCPE(dw7x7+res) -> fc1+BN -> MRConv4d(K=2) -> gc(2C->C)+BN+GELU -> fc2+BN
// B=32, C=192, H=W=56. d_in/d_out FLOAT32; intermediates bf16.
//
//   fold:   BN-fold weights -> W1f[192][192], Wgf[192][384], W2f[192][192] (bf16), biases fp32
//   dwconv: v6 EXACT (round-9 measured 72us, WRITE exactly 37.6MB): (b,16ch,8rows) blocks,
//           30.6KB bf16 LDS, kh-outer 7+7 weights, 4 blocks/CU, 32B-chunk stores
//   gemm1:  y1 = y0*W1f^T  (D[p][o], MINW=3, grid 768) -> y1 bf16 pm (d_out scratch)
//   gemm2:  MODE 3 - xj FUSED into chunk-2 staging (max-relative from y1 on the fly),
//           y2 = GELU([y1|xj]*Wgf) -> y2 bf16 pm
//   gemm3:  out = y2*W2f^T (swapped ops, D[o][p]) -> d_out f32 channel-major

#define CC   192
#define HW   3136
#define NB   32

using short8 = __attribute__((ext_vector_type(8))) short;
using f32x4  = __attribute__((ext_vector_type(4))) float;

__device__ __forceinline__ float bf2f(short s) {
  union { unsigned u; float f; } x; x.u = ((unsigned)(unsigned short)s) << 16; return x.f;
}
__device__ __forceinline__ short f2bf(float f) {
  __hip_bfloat16 h = __float2bfloat16(f);
  return *reinterpret_cast<short*>(&h);
}
__device__ __forceinline__ float geluf(float v) {
  return 0.5f * v * (1.0f + erff(v * 0.70710678118654752f));
}
__device__ __forceinline__ void gl2lds(const char* g, char* l) {
  __builtin_amdgcn_global_load_lds(
      (const __attribute__((address_space(1))) void*)g,
      (__attribute__((address_space(3))) void*)l, 16, 0, 0);
}

// ---------------- fold: BN into weights/bias ----------------
__global__ void __launch_bounds__(256) fold_kernel(
    const float* __restrict__ fc1_w, const float* __restrict__ fc1_b,
    const float* __restrict__ bn1_g, const float* __restrict__ bn1_b,
    const float* __restrict__ bn1_m, const float* __restrict__ bn1_v,
    const float* __restrict__ gc_w,  const float* __restrict__ gc_b,
    const float* __restrict__ bng_g, const float* __restrict__ bng_b,
    const float* __restrict__ bng_m, const float* __restrict__ bng_v,
    const float* __restrict__ fc2_w, const float* __restrict__ fc2_b,
    const float* __restrict__ bn2_g, const float* __restrict__ bn2_b,
    const float* __restrict__ bn2_m, const float* __restrict__ bn2_v,
    __hip_bfloat16* __restrict__ W1f, __hip_bfloat16* __restrict__ Wgf, __hip_bfloat16* __restrict__ W2f,
    float* __restrict__ b1f, float* __restrict__ bgf, float* __restrict__ b2f) {
  int gt = blockIdx.x * 256 + threadIdx.x;
  if (gt < 3 * CC) {
    int which = gt / CC, o = gt - which * CC;
    const float *G, *Bt, *M, *V, *Bi; float* dst;
    if (which == 0)      { G = bn1_g; Bt = bn1_b; M = bn1_m; V = bn1_v; Bi = fc1_b; dst = b1f; }
    else if (which == 1) { G = bng_g; Bt = bng_b; M = bng_m; V = bng_v; Bi = gc_b;  dst = bgf; }
    else                 { G = bn2_g; Bt = bn2_b; M = bn2_m; V = bn2_v; Bi = fc2_b; dst = b2f; }
    float inv = G[o] * rsqrtf(V[o] + 1e-5f);
    dst[o] = Bi[o] * inv + Bt[o] - M[o] * inv;
  }
  int i = gt;
  if (i < CC * CC) {
    int o = i / CC;
    float inv = bn1_g[o] * rsqrtf(bn1_v[o] + 1e-5f);
    W1f[i] = __float2bfloat16(fc1_w[i] * inv);
  } else if (i < CC * CC + CC * 2 * CC) {
    int j = i - CC * CC; int o = j / (2 * CC);
    float inv = bng_g[o] * rsqrtf(bng_v[o] + 1e-5f);
    Wgf[j] = __float2bfloat16(gc_w[j] * inv);
  } else if (i < CC * CC * 4) {
    int j = i - CC * CC * 3; int o = j / CC;
    float inv = bn2_g[o] * rsqrtf(bn2_v[o] + 1e-5f);
    W2f[j] = __float2bfloat16(fc2_w[j] * inv);
  }
}

// ---------------- dw 7x7 + bias + residual -> PIXEL-MAJOR bf16 (v6, round-9 exact) ----------------
#define CSTR 956
__global__ void __launch_bounds__(256, 4) dwconv_kernel(
    const float* __restrict__ x, const float* __restrict__ cw,
    const float* __restrict__ cb, __hip_bfloat16* __restrict__ y0pm) {
  __shared__ short in_t[16 * CSTR];            // 30592 B
  const int t = threadIdx.x;
  int bb = blockIdx.x;
  const int rs = bb % 7;  bb /= 7;
  const int cg = bb % 12; bb /= 12;
  const int b  = bb;
  const int h0 = rs * 8;

  for (int i = t; i < 16 * CSTR / 8; i += 256) ((int4*)in_t)[i] = int4{0, 0, 0, 0};
  __syncthreads();

  // stage rows h0-3 .. h0+10 (14 rows), 16 channels, bf16
  for (int it = t; it < 16 * 14 * 14; it += 256) {
    int w4 = it % 14, rr = (it / 14) % 14, c = it / 196;
    int gh = h0 - 3 + rr;
    if (gh >= 0 && gh < 56) {
      float4 v = *(const float4*)(x + ((size_t)(b * CC + cg * 16 + c) * 56 + gh) * 56 + w4 * 4);
      short4 s4 = { f2bf(v.x), f2bf(v.y), f2bf(v.z), f2bf(v.w) };
      *(short4*)(in_t + c * CSTR + rr * 68 + 4 + w4 * 4) = s4;
    }
  }
  __syncthreads();

  const int c = t & 15, g = t >> 4;
  const int cgx = g % 7, rh = g / 7;           // g<14 active
  if (g < 14) {
    const float* wp = cw + (cg * 16 + c) * 49;
    const float bias = cb[cg * 16 + c];
    const short* base = in_t + c * CSTR + rh * 4 * 68 + cgx * 8;
    float acc[4][8] = {};
    float wr[7], wn[7];
#pragma unroll
    for (int i = 0; i < 7; ++i) wr[i] = wp[i];
#pragma unroll
    for (int kh = 0; kh < 7; ++kh) {
      if (kh < 6) {
#pragma unroll
        for (int i = 0; i < 7; ++i) wn[i] = wp[(kh + 1) * 7 + i];
      }
      if (kh == 3) wr[3] += 1.0f;              // residual = center tap + 1
#pragma unroll
      for (int r = 0; r < 4; ++r) {
        const short* rp = base + (r + kh) * 68;
        int2 q0 = *(const int2*)(rp);
        int2 q1 = *(const int2*)(rp + 4);
        int2 q2 = *(const int2*)(rp + 8);
        int2 q3 = *(const int2*)(rp + 12);
        int dw[8] = { q0.x, q0.y, q1.x, q1.y, q2.x, q2.y, q3.x, q3.y };
        float v[16];
#pragma unroll
        for (int q = 0; q < 8; ++q) {
          union { int i; float f; } lo, hi;
          lo.i = dw[q] << 16; hi.i = dw[q] & 0xffff0000;
          v[q * 2] = lo.f; v[q * 2 + 1] = hi.f;
        }
#pragma unroll
        for (int kw = 0; kw < 7; ++kw) {
          float wv = wr[kw];
#pragma unroll
          for (int ww = 0; ww < 8; ++ww)
            acc[r][ww] = fmaf(wv, v[ww + kw + 1], acc[r][ww]);
        }
      }
#pragma unroll
      for (int i = 0; i < 7; ++i) wr[i] = wn[i];
    }
    short* dst = (short*)y0pm + ((size_t)b * HW + (size_t)(h0 + rh * 4) * 56 + cgx * 8) * CC
                 + cg * 16 + c;
#pragma unroll
    for (int r = 0; r < 4; ++r)
#pragma unroll
      for (int ww = 0; ww < 8; ++ww)
        dst[(size_t)(r * 56 + ww) * CC] = f2bf(acc[r][ww] + bias);
  }
}

// ---------------- gemm: BM=64, gl_lds staging (pre-swizzled src), hoisted weights ----------------
// MODE 0: bf16 pm out; MODE 2: swapped ops -> f32 channel-major;
// MODE 3: NCHUNK=2, chunk2 = FUSED xj (max-relative from y1, reg-staged), GELU epilogue.
__device__ __forceinline__ void stage_xj(char* dst, const short* y1b, int hwbase, int t) {
#pragma unroll 2
  for (int j = 0; j < 6; ++j) {
    int idx = j * 4096 + t * 16;
    int p = idx / 384, qd = idx - p * 384;
    int co = qd >> 1;
    int hwl = hwbase + p;
    int h = hwl / 56, w = hwl - h * 56;
    int hp = (h >= 54) ? h - 54 : h + 2;
    int hm = (h < 2) ? h + 54 : h - 2;
    int wp_ = (w >= 54) ? w - 54 : w + 2;
    int wm_ = (w < 2) ? w + 54 : w - 2;
    short8 c0 = *(const short8*)(y1b + (size_t)hwl * CC + co);
    short8 n1 = *(const short8*)(y1b + (size_t)(hp * 56 + w) * CC + co);
    short8 n2 = *(const short8*)(y1b + (size_t)(hm * 56 + w) * CC + co);
    short8 n3 = *(const short8*)(y1b + (size_t)(h * 56 + wp_) * CC + co);
    short8 n4 = *(const short8*)(y1b + (size_t)(h * 56 + wm_) * CC + co);
    short8 res;
#pragma unroll
    for (int q = 0; q < 8; ++q) {
      float m = fmaxf(fmaxf(bf2f(n1[q]), bf2f(n2[q])), fmaxf(bf2f(n3[q]), bf2f(n4[q])));
      res[q] = f2bf(fmaxf(m - bf2f(c0[q]), 0.0f));
    }
    *(short8*)(dst + p * 384 + (qd ^ ((p & 7) << 4))) = res;
  }
}

template<int NCHUNK, int MODE, int MINW>
__global__ void __launch_bounds__(256, MINW) gemm_kernel(
    const __hip_bfloat16* __restrict__ actA, const __hip_bfloat16* __restrict__ actB,
    const __hip_bfloat16* __restrict__ Wf, const float* __restrict__ bfv,
    void* __restrict__ outp) {
  __shared__ char smem[2][24576];
  const int t = threadIdx.x;
  const int lane = t & 63, w = t >> 6;
  const int lrow = lane & 15, lhi = lane >> 4;
  constexpr int K_IN = NCHUNK * 192;
  constexpr int NT = NB * 49;          // 1568 pixel tiles of 64

  // per-thread pre-swizzled global source offsets for 6 gl_lds transfers
  int goff[6];
#pragma unroll
  for (int j = 0; j < 6; ++j) {
    int idx = j * 4096 + t * 16;
    int p = idx / 384, qd = idx - p * 384;
    goff[j] = p * 384 + (qd ^ ((p & 7) << 4));
  }

  float bw0[3];
  float bw2[3][4];
  if (MODE != 2) {
#pragma unroll
    for (int wi = 0; wi < 3; ++wi) bw0[wi] = bfv[w * 48 + wi * 16 + lrow];
  } else {
#pragma unroll
    for (int wi = 0; wi < 3; ++wi)
#pragma unroll
      for (int r = 0; r < 4; ++r) bw2[wi][r] = bfv[w * 48 + wi * 16 + lhi * 4 + r];
  }

  // hoist ALL weights for this wave's 48-o slice (both chunks for NCHUNK=2)
  short8 wreg[NCHUNK][6][3];
#pragma unroll
  for (int c = 0; c < NCHUNK; ++c)
#pragma unroll
    for (int kk = 0; kk < 6; ++kk)
#pragma unroll
      for (int wi = 0; wi < 3; ++wi) {
        int o = w * 48 + wi * 16 + lrow;
        wreg[c][kk][wi] = *(const short8*)((const short*)Wf +
            (size_t)o * K_IN + c * 192 + kk * 32 + lhi * 8);
      }

  const int step = gridDim.x;
  int tile = blockIdx.x;
  // prologue: stage (tile, chunk0) into buf0
  {
    const char* src = (const char*)actA + (size_t)tile * 24576;
#pragma unroll
    for (int j = 0; j < 6; ++j)
      gl2lds(src + goff[j], smem[0] + j * 4096 + w * 1024);
  }
  __syncthreads();
  int cur = 0;

  while (tile < NT) {
    const int tnext = tile + step;
    const int bimg = tile / 49;
    const int hwbase = (tile - bimg * 49) * 64;
    const short* y1b = (const short*)actA + (size_t)bimg * HW * CC;
    f32x4 acc[4][3] = {};
#pragma unroll
    for (int c = 0; c < NCHUNK; ++c) {
      // stage the NEXT chunk/tile into the other buffer
      if (MODE == 3 && c == 0) {
        stage_xj(smem[cur ^ 1], y1b, hwbase, t);         // fused max-relative
      } else {
        const char* nsrc = nullptr;
        if (c + 1 < NCHUNK)      nsrc = (const char*)actB + (size_t)tile * 24576;
        else if (tnext < NT)     nsrc = (const char*)actA + (size_t)tnext * 24576;
        if (nsrc) {
#pragma unroll
          for (int j = 0; j < 6; ++j)
            gl2lds(nsrc + goff[j], smem[cur ^ 1] + j * 4096 + w * 1024);
        }
      }
      // compute current buffer (gl_lds loads stay in flight until the barrier)
#pragma unroll
      for (int kk = 0; kk < 6; ++kk) {
        short8 af[4];
#pragma unroll
        for (int ai = 0; ai < 4; ++ai) {
          int p = ai * 16 + lrow;
          af[ai] = *(const short8*)(smem[cur] + p * 384 + ((kk * 64 + lhi * 16) ^ ((p & 7) << 4)));
        }
#pragma unroll
        for (int ai = 0; ai < 4; ++ai)
#pragma unroll
          for (int wi = 0; wi < 3; ++wi)
            acc[ai][wi] = (MODE == 2)
                ? __builtin_amdgcn_mfma_f32_16x16x32_bf16(wreg[c][kk][wi], af[ai], acc[ai][wi], 0, 0, 0)
                : __builtin_amdgcn_mfma_f32_16x16x32_bf16(af[ai], wreg[c][kk][wi], acc[ai][wi], 0, 0, 0);
      }
      __syncthreads();
      cur ^= 1;
    }
    // epilogue
    if (MODE != 2) {
      short* ob = (short*)outp + (size_t)tile * 64 * CC;
#pragma unroll
      for (int wi = 0; wi < 3; ++wi) {
        int o = w * 48 + wi * 16 + lrow;
#pragma unroll
        for (int ai = 0; ai < 4; ++ai)
#pragma unroll
          for (int r = 0; r < 4; ++r) {
            int p = ai * 16 + lhi * 4 + r;
            float v = acc[ai][wi][r] + bw0[wi];
            if (MODE == 3) v = geluf(v);
            ob[(size_t)p * CC + o] = f2bf(v);
          }
      }
    } else {
      float* ob = (float*)outp + (size_t)bimg * CC * HW + hwbase;
#pragma unroll
      for (int wi = 0; wi < 3; ++wi)
#pragma unroll
        for (int r = 0; r < 4; ++r) {
          int o = w * 48 + wi * 16 + lhi * 4 + r;
#pragma unroll
          for (int ai = 0; ai < 4; ++ai)
            ob[(size_t)o * HW + ai * 16 + lrow] = acc[ai][wi][r] + bw2[wi][r];
        }
    }
    tile = tnext;
  }
}

extern "C" void kernel_launch(void* const* d_in, const int* in_sizes, int n_in,
                              void* d_out, int out_size, void* d_ws, size_t ws_size,
                              hipStream_t stream) {
  const float* x     = (const float*)d_in[0];
  const float* cpe_w = (const float*)d_in[1];
  const float* cpe_b = (const float*)d_in[2];
  const float* fc1_w = (const float*)d_in[3];
  const float* fc1_b = (const float*)d_in[4];
  const float* bn1_g = (const float*)d_in[5];
  const float* bn1_b = (const float*)d_in[6];
  const float* bn1_m = (const float*)d_in[7];
  const float* bn1_v = (const float*)d_in[8];
  const float* gc_w  = (const float*)d_in[9];
  const float* gc_b  = (const float*)d_in[10];
  const float* bng_g = (const float*)d_in[11];
  const float* bng_b = (const float*)d_in[12];
  const float* bng_m = (const float*)d_in[13];
  const float* bng_v = (const float*)d_in[14];
  const float* fc2_w = (const float*)d_in[15];
  const float* fc2_b = (const float*)d_in[16];
  const float* bn2_g = (const float*)d_in[17];
  const float* bn2_b = (const float*)d_in[18];
  const float* bn2_m = (const float*)d_in[19];
  const float* bn2_v = (const float*)d_in[20];

  if (ws_size < 77594624) return;
  char* ws = (char*)d_ws;
  __hip_bfloat16* W1f = (__hip_bfloat16*)(ws);
  __hip_bfloat16* Wgf = (__hip_bfloat16*)(ws + 73728);
  __hip_bfloat16* W2f = (__hip_bfloat16*)(ws + 221184);
  float* b1f = (float*)(ws + 294912);
  float* bgf = (float*)(ws + 295680);
  float* b2f = (float*)(ws + 296448);
  __hip_bfloat16* y0  = (__hip_bfloat16*)(ws + 524288);       // pixel-major; reused as y2
  __hip_bfloat16* y1  = (__hip_bfloat16*)d_out;               // d_out as bf16 scratch
  float* out = (float*)d_out;

  fold_kernel<<<576, 256, 0, stream>>>(fc1_w, fc1_b, bn1_g, bn1_b, bn1_m, bn1_v,
      gc_w, gc_b, bng_g, bng_b, bng_m, bng_v, fc2_w, fc2_b, bn2_g, bn2_b, bn2_m, bn2_v,
      W1f, Wgf, W2f, b1f, bgf, b2f);
  dwconv_kernel<<<NB * 12 * 7, 256, 0, stream>>>(x, cpe_w, cpe_b, y0);
  gemm_kernel<1, 0, 3><<<768, 256, 0, stream>>>(y0, nullptr, W1f, b1f, y1);
  gemm_kernel<2, 3, 2><<<512, 256, 0, stream>>>(y1, nullptr, Wgf, bgf, y0);
  gemm_kernel<1, 2, 2><<<512, 256, 0, stream>>>(y0, nullptr, W2f, b2f, out);
}

// Round 14
// 163.124 us; speedup vs baseline: 1.1076x; 1.1076x over previous
//
#include <hip/hip_runtime.h>
#include <hip/hip_bf16.h>

// Grapher block: RepCPE(dw7x7+res) -> fc1+BN -> MRConv4d(K=2) -> gc(2C->C)+BN+GELU -> fc2+BN
// B=32, C=192, H=W=56. d_in/d_out FLOAT32; intermediates bf16.
//
//   fold:   BN-fold weights -> W1f[192][192], Wgf[192][384], W2f[192][192] (bf16), biases fp32
//   dwconv: v6 EXACT (round-9/13 measured 72.5us): (b,16ch,8rows) blocks, 30.6KB bf16 LDS,
//           kh-outer 7+7 weights, 4 blocks/CU, 32B-chunk stores -> y0 pixel-major bf16
//   gemm1:  y1 = y0*W1f^T  (D[p][o], MINW=2, grid 512) -> y1 bf16 pm (d_out scratch)
//   gemm2:  MODE 3 - xj FUSED into chunk-2 staging (max-relative from y1 on the fly),
//           y2 = GELU([y1|xj]*Wgf) -> y2 bf16 pm
//   gemm3:  out = y2*W2f^T (swapped ops, D[o][p]) -> d_out f32 channel-major
//
// Round 14 = round-12 gemm config (MINW=2 everywhere; round-13's MINW=3 starved the
// register allocator to 84 VGPR -> weight spill to scratch -> 140us gemm1) + round-13's
// v6-exact dwconv. Pure best-of-both revert; no new experiments.

#define CC   192
#define HW   3136
#define NB   32

using short8 = __attribute__((ext_vector_type(8))) short;
using f32x4  = __attribute__((ext_vector_type(4))) float;

__device__ __forceinline__ float bf2f(short s) {
  union { unsigned u; float f; } x; x.u = ((unsigned)(unsigned short)s) << 16; return x.f;
}
__device__ __forceinline__ short f2bf(float f) {
  __hip_bfloat16 h = __float2bfloat16(f);
  return *reinterpret_cast<short*>(&h);
}
__device__ __forceinline__ float geluf(float v) {
  return 0.5f * v * (1.0f + erff(v * 0.70710678118654752f));
}
__device__ __forceinline__ void gl2lds(const char* g, char* l) {
  __builtin_amdgcn_global_load_lds(
      (const __attribute__((address_space(1))) void*)g,
      (__attribute__((address_space(3))) void*)l, 16, 0, 0);
}

// ---------------- fold: BN into weights/bias ----------------
__global__ void __launch_bounds__(256) fold_kernel(
    const float* __restrict__ fc1_w, const float* __restrict__ fc1_b,
    const float* __restrict__ bn1_g, const float* __restrict__ bn1_b,
    const float* __restrict__ bn1_m, const float* __restrict__ bn1_v,
    const float* __restrict__ gc_w,  const float* __restrict__ gc_b,
    const float* __restrict__ bng_g, const float* __restrict__ bng_b,
    const float* __restrict__ bng_m, const float* __restrict__ bng_v,
    const float* __restrict__ fc2_w, const float* __restrict__ fc2_b,
    const float* __restrict__ bn2_g, const float* __restrict__ bn2_b,
    const float* __restrict__ bn2_m, const float* __restrict__ bn2_v,
    __hip_bfloat16* __restrict__ W1f, __hip_bfloat16* __restrict__ Wgf, __hip_bfloat16* __restrict__ W2f,
    float* __restrict__ b1f, float* __restrict__ bgf, float* __restrict__ b2f) {
  int gt = blockIdx.x * 256 + threadIdx.x;
  if (gt < 3 * CC) {
    int which = gt / CC, o = gt - which * CC;
    const float *G, *Bt, *M, *V, *Bi; float* dst;
    if (which == 0)      { G = bn1_g; Bt = bn1_b; M = bn1_m; V = bn1_v; Bi = fc1_b; dst = b1f; }
    else if (which == 1) { G = bng_g; Bt = bng_b; M = bng_m; V = bng_v; Bi = gc_b;  dst = bgf; }
    else                 { G = bn2_g; Bt = bn2_b; M = bn2_m; V = bn2_v; Bi = fc2_b; dst = b2f; }
    float inv = G[o] * rsqrtf(V[o] + 1e-5f);
    dst[o] = Bi[o] * inv + Bt[o] - M[o] * inv;
  }
  int i = gt;
  if (i < CC * CC) {
    int o = i / CC;
    float inv = bn1_g[o] * rsqrtf(bn1_v[o] + 1e-5f);
    W1f[i] = __float2bfloat16(fc1_w[i] * inv);
  } else if (i < CC * CC + CC * 2 * CC) {
    int j = i - CC * CC; int o = j / (2 * CC);
    float inv = bng_g[o] * rsqrtf(bng_v[o] + 1e-5f);
    Wgf[j] = __float2bfloat16(gc_w[j] * inv);
  } else if (i < CC * CC * 4) {
    int j = i - CC * CC * 3; int o = j / CC;
    float inv = bn2_g[o] * rsqrtf(bn2_v[o] + 1e-5f);
    W2f[j] = __float2bfloat16(fc2_w[j] * inv);
  }
}

// ---------------- dw 7x7 + bias + residual -> PIXEL-MAJOR bf16 (v6, round-9 exact) ----------------
#define CSTR 956
__global__ void __launch_bounds__(256, 4) dwconv_kernel(
    const float* __restrict__ x, const float* __restrict__ cw,
    const float* __restrict__ cb, __hip_bfloat16* __restrict__ y0pm) {
  __shared__ short in_t[16 * CSTR];            // 30592 B
  const int t = threadIdx.x;
  int bb = blockIdx.x;
  const int rs = bb % 7;  bb /= 7;
  const int cg = bb % 12; bb /= 12;
  const int b  = bb;
  const int h0 = rs * 8;

  for (int i = t; i < 16 * CSTR / 8; i += 256) ((int4*)in_t)[i] = int4{0, 0, 0, 0};
  __syncthreads();

  // stage rows h0-3 .. h0+10 (14 rows), 16 channels, bf16
  for (int it = t; it < 16 * 14 * 14; it += 256) {
    int w4 = it % 14, rr = (it / 14) % 14, c = it / 196;
    int gh = h0 - 3 + rr;
    if (gh >= 0 && gh < 56) {
      float4 v = *(const float4*)(x + ((size_t)(b * CC + cg * 16 + c) * 56 + gh) * 56 + w4 * 4);
      short4 s4 = { f2bf(v.x), f2bf(v.y), f2bf(v.z), f2bf(v.w) };
      *(short4*)(in_t + c * CSTR + rr * 68 + 4 + w4 * 4) = s4;
    }
  }
  __syncthreads();

  const int c = t & 15, g = t >> 4;
  const int cgx = g % 7, rh = g / 7;           // g<14 active
  if (g < 14) {
    const float* wp = cw + (cg * 16 + c) * 49;
    const float bias = cb[cg * 16 + c];
    const short* base = in_t + c * CSTR + rh * 4 * 68 + cgx * 8;
    float acc[4][8] = {};
    float wr[7], wn[7];
#pragma unroll
    for (int i = 0; i < 7; ++i) wr[i] = wp[i];
#pragma unroll
    for (int kh = 0; kh < 7; ++kh) {
      if (kh < 6) {
#pragma unroll
        for (int i = 0; i < 7; ++i) wn[i] = wp[(kh + 1) * 7 + i];
      }
      if (kh == 3) wr[3] += 1.0f;              // residual = center tap + 1
#pragma unroll
      for (int r = 0; r < 4; ++r) {
        const short* rp = base + (r + kh) * 68;
        int2 q0 = *(const int2*)(rp);
        int2 q1 = *(const int2*)(rp + 4);
        int2 q2 = *(const int2*)(rp + 8);
        int2 q3 = *(const int2*)(rp + 12);
        int dw[8] = { q0.x, q0.y, q1.x, q1.y, q2.x, q2.y, q3.x, q3.y };
        float v[16];
#pragma unroll
        for (int q = 0; q < 8; ++q) {
          union { int i; float f; } lo, hi;
          lo.i = dw[q] << 16; hi.i = dw[q] & 0xffff0000;
          v[q * 2] = lo.f; v[q * 2 + 1] = hi.f;
        }
#pragma unroll
        for (int kw = 0; kw < 7; ++kw) {
          float wv = wr[kw];
#pragma unroll
          for (int ww = 0; ww < 8; ++ww)
            acc[r][ww] = fmaf(wv, v[ww + kw + 1], acc[r][ww]);
        }
      }
#pragma unroll
      for (int i = 0; i < 7; ++i) wr[i] = wn[i];
    }
    short* dst = (short*)y0pm + ((size_t)b * HW + (size_t)(h0 + rh * 4) * 56 + cgx * 8) * CC
                 + cg * 16 + c;
#pragma unroll
    for (int r = 0; r < 4; ++r)
#pragma unroll
      for (int ww = 0; ww < 8; ++ww)
        dst[(size_t)(r * 56 + ww) * CC] = f2bf(acc[r][ww] + bias);
  }
}

// ---------------- gemm: BM=64, gl_lds staging (pre-swizzled src), hoisted weights ----------------
// MODE 0: bf16 pm out; MODE 2: swapped ops -> f32 channel-major;
// MODE 3: NCHUNK=2, chunk2 = FUSED xj (max-relative from y1, reg-staged), GELU epilogue.
__device__ __forceinline__ void stage_xj(char* dst, const short* y1b, int hwbase, int t) {
#pragma unroll 2
  for (int j = 0; j < 6; ++j) {
    int idx = j * 4096 + t * 16;
    int p = idx / 384, qd = idx - p * 384;
    int co = qd >> 1;
    int hwl = hwbase + p;
    int h = hwl / 56, w = hwl - h * 56;
    int hp = (h >= 54) ? h - 54 : h + 2;
    int hm = (h < 2) ? h + 54 : h - 2;
    int wp_ = (w >= 54) ? w - 54 : w + 2;
    int wm_ = (w < 2) ? w + 54 : w - 2;
    short8 c0 = *(const short8*)(y1b + (size_t)hwl * CC + co);
    short8 n1 = *(const short8*)(y1b + (size_t)(hp * 56 + w) * CC + co);
    short8 n2 = *(const short8*)(y1b + (size_t)(hm * 56 + w) * CC + co);
    short8 n3 = *(const short8*)(y1b + (size_t)(h * 56 + wp_) * CC + co);
    short8 n4 = *(const short8*)(y1b + (size_t)(h * 56 + wm_) * CC + co);
    short8 res;
#pragma unroll
    for (int q = 0; q < 8; ++q) {
      float m = fmaxf(fmaxf(bf2f(n1[q]), bf2f(n2[q])), fmaxf(bf2f(n3[q]), bf2f(n4[q])));
      res[q] = f2bf(fmaxf(m - bf2f(c0[q]), 0.0f));
    }
    *(short8*)(dst + p * 384 + (qd ^ ((p & 7) << 4))) = res;
  }
}

template<int NCHUNK, int MODE, int MINW>
__global__ void __launch_bounds__(256, MINW) gemm_kernel(
    const __hip_bfloat16* __restrict__ actA, const __hip_bfloat16* __restrict__ actB,
    const __hip_bfloat16* __restrict__ Wf, const float* __restrict__ bfv,
    void* __restrict__ outp) {
  __shared__ char smem[2][24576];
  const int t = threadIdx.x;
  const int lane = t & 63, w = t >> 6;
  const int lrow = lane & 15, lhi = lane >> 4;
  constexpr int K_IN = NCHUNK * 192;
  constexpr int NT = NB * 49;          // 1568 pixel tiles of 64

  // per-thread pre-swizzled global source offsets for 6 gl_lds transfers
  int goff[6];
#pragma unroll
  for (int j = 0; j < 6; ++j) {
    int idx = j * 4096 + t * 16;
    int p = idx / 384, qd = idx - p * 384;
    goff[j] = p * 384 + (qd ^ ((p & 7) << 4));
  }

  float bw0[3];
  float bw2[3][4];
  if (MODE != 2) {
#pragma unroll
    for (int wi = 0; wi < 3; ++wi) bw0[wi] = bfv[w * 48 + wi * 16 + lrow];
  } else {
#pragma unroll
    for (int wi = 0; wi < 3; ++wi)
#pragma unroll
      for (int r = 0; r < 4; ++r) bw2[wi][r] = bfv[w * 48 + wi * 16 + lhi * 4 + r];
  }

  // hoist ALL weights for this wave's 48-o slice (both chunks for NCHUNK=2)
  short8 wreg[NCHUNK][6][3];
#pragma unroll
  for (int c = 0; c < NCHUNK; ++c)
#pragma unroll
    for (int kk = 0; kk < 6; ++kk)
#pragma unroll
      for (int wi = 0; wi < 3; ++wi) {
        int o = w * 48 + wi * 16 + lrow;
        wreg[c][kk][wi] = *(const short8*)((const short*)Wf +
            (size_t)o * K_IN + c * 192 + kk * 32 + lhi * 8);
      }

  const int step = gridDim.x;
  int tile = blockIdx.x;
  // prologue: stage (tile, chunk0) into buf0
  {
    const char* src = (const char*)actA + (size_t)tile * 24576;
#pragma unroll
    for (int j = 0; j < 6; ++j)
      gl2lds(src + goff[j], smem[0] + j * 4096 + w * 1024);
  }
  __syncthreads();
  int cur = 0;

  while (tile < NT) {
    const int tnext = tile + step;
    const int bimg = tile / 49;
    const int hwbase = (tile - bimg * 49) * 64;
    const short* y1b = (const short*)actA + (size_t)bimg * HW * CC;
    f32x4 acc[4][3] = {};
#pragma unroll
    for (int c = 0; c < NCHUNK; ++c) {
      // stage the NEXT chunk/tile into the other buffer
      if (MODE == 3 && c == 0) {
        stage_xj(smem[cur ^ 1], y1b, hwbase, t);         // fused max-relative
      } else {
        const char* nsrc = nullptr;
        if (c + 1 < NCHUNK)      nsrc = (const char*)actB + (size_t)tile * 24576;
        else if (tnext < NT)     nsrc = (const char*)actA + (size_t)tnext * 24576;
        if (nsrc) {
#pragma unroll
          for (int j = 0; j < 6; ++j)
            gl2lds(nsrc + goff[j], smem[cur ^ 1] + j * 4096 + w * 1024);
        }
      }
      // compute current buffer (gl_lds loads stay in flight until the barrier)
#pragma unroll
      for (int kk = 0; kk < 6; ++kk) {
        short8 af[4];
#pragma unroll
        for (int ai = 0; ai < 4; ++ai) {
          int p = ai * 16 + lrow;
          af[ai] = *(const short8*)(smem[cur] + p * 384 + ((kk * 64 + lhi * 16) ^ ((p & 7) << 4)));
        }
#pragma unroll
        for (int ai = 0; ai < 4; ++ai)
#pragma unroll
          for (int wi = 0; wi < 3; ++wi)
            acc[ai][wi] = (MODE == 2)
                ? __builtin_amdgcn_mfma_f32_16x16x32_bf16(wreg[c][kk][wi], af[ai], acc[ai][wi], 0, 0, 0)
                : __builtin_amdgcn_mfma_f32_16x16x32_bf16(af[ai], wreg[c][kk][wi], acc[ai][wi], 0, 0, 0);
      }
      __syncthreads();
      cur ^= 1;
    }
    // epilogue
    if (MODE != 2) {
      short* ob = (short*)outp + (size_t)tile * 64 * CC;
#pragma unroll
      for (int wi = 0; wi < 3; ++wi) {
        int o = w * 48 + wi * 16 + lrow;
#pragma unroll
        for (int ai = 0; ai < 4; ++ai)
#pragma unroll
          for (int r = 0; r < 4; ++r) {
            int p = ai * 16 + lhi * 4 + r;
            float v = acc[ai][wi][r] + bw0[wi];
            if (MODE == 3) v = geluf(v);
            ob[(size_t)p * CC + o] = f2bf(v);
          }
      }
    } else {
      float* ob = (float*)outp + (size_t)bimg * CC * HW + hwbase;
#pragma unroll
      for (int wi = 0; wi < 3; ++wi)
#pragma unroll
        for (int r = 0; r < 4; ++r) {
          int o = w * 48 + wi * 16 + lhi * 4 + r;
#pragma unroll
          for (int ai = 0; ai < 4; ++ai)
            ob[(size_t)o * HW + ai * 16 + lrow] = acc[ai][wi][r] + bw2[wi][r];
        }
    }
    tile = tnext;
  }
}

extern "C" void kernel_launch(void* const* d_in, const int* in_sizes, int n_in,
                              void* d_out, int out_size, void* d_ws, size_t ws_size,
                              hipStream_t stream) {
  const float* x     = (const float*)d_in[0];
  const float* cpe_w = (const float*)d_in[1];
  const float* cpe_b = (const float*)d_in[2];
  const float* fc1_w = (const float*)d_in[3];
  const float* fc1_b = (const float*)d_in[4];
  const float* bn1_g = (const float*)d_in[5];
  const float* bn1_b = (const float*)d_in[6];
  const float* bn1_m = (const float*)d_in[7];
  const float* bn1_v = (const float*)d_in[8];
  const float* gc_w  = (const float*)d_in[9];
  const float* gc_b  = (const float*)d_in[10];
  const float* bng_g = (const float*)d_in[11];
  const float* bng_b = (const float*)d_in[12];
  const float* bng_m = (const float*)d_in[13];
  const float* bng_v = (const float*)d_in[14];
  const float* fc2_w = (const float*)d_in[15];
  const float* fc2_b = (const float*)d_in[16];
  const float* bn2_g = (const float*)d_in[17];
  const float* bn2_b = (const float*)d_in[18];
  const float* bn2_m = (const float*)d_in[19];
  const float* bn2_v = (const float*)d_in[20];

  if (ws_size < 77594624) return;
  char* ws = (char*)d_ws;
  __hip_bfloat16* W1f = (__hip_bfloat16*)(ws);
  __hip_bfloat16* Wgf = (__hip_bfloat16*)(ws + 73728);
  __hip_bfloat16* W2f = (__hip_bfloat16*)(ws + 221184);
  float* b1f = (float*)(ws + 294912);
  float* bgf = (float*)(ws + 295680);
  float* b2f = (float*)(ws + 296448);
  __hip_bfloat16* y0  = (__hip_bfloat16*)(ws + 524288);       // pixel-major; reused as y2
  __hip_bfloat16* y1  = (__hip_bfloat16*)d_out;               // d_out as bf16 scratch
  float* out = (float*)d_out;

  fold_kernel<<<576, 256, 0, stream>>>(fc1_w, fc1_b, bn1_g, bn1_b, bn1_m, bn1_v,
      gc_w, gc_b, bng_g, bng_b, bng_m, bng_v, fc2_w, fc2_b, bn2_g, bn2_b, bn2_m, bn2_v,
      W1f, Wgf, W2f, b1f, bgf, b2f);
  dwconv_kernel<<<NB * 12 * 7, 256, 0, stream>>>(x, cpe_w, cpe_b, y0);
  gemm_kernel<1, 0, 2><<<512, 256, 0, stream>>>(y0, nullptr, W1f, b1f, y1);
  gemm_kernel<2, 3, 2><<<512, 256, 0, stream>>>(y1, nullptr, Wgf, bgf, y0);
  gemm_kernel<1, 2, 2><<<512, 256, 0, stream>>>(y0, nullptr, W2f, b2f, out);
}